// Round 1
// baseline (4652.848 us; speedup 1.0000x reference)
//
#include <hip/hip_runtime.h>

// LSTM scan, B=64, T=16384, H=32, I=O=1, fp32.
// One wave (64 lanes) per batch PAIR: lane l owns hidden unit j=l&31 of batch
// (2*blockIdx + (l>>5)), holding all 4 gate rows of W_hh in VGPRs (128 regs).
// h is exchanged through a per-wave LDS ring buffer (32-step history), which
// doubles as the input to the per-chunk output-projection epilogue.
// Block = exactly 1 wave -> no __syncthreads needed (same-wave DS ops are
// in-order; compiler inserts lgkmcnt waits).

#define HID 32
#define CHUNK 32

typedef float f2 __attribute__((ext_vector_type(2)));
typedef float f4 __attribute__((ext_vector_type(4)));

__device__ __forceinline__ float fsig(float v) {
    // sigmoid(v) = 1 / (1 + exp2(-v*log2(e)))
    float e = __builtin_amdgcn_exp2f(v * -1.44269504088896340736f);
    return __builtin_amdgcn_rcpf(1.0f + e);
}
__device__ __forceinline__ float ftanh(float v) {
    // tanh(v) = 2/(1+exp2(-2v*log2(e))) - 1
    float e = __builtin_amdgcn_exp2f(v * -2.88539008177792681472f);
    float r = __builtin_amdgcn_rcpf(1.0f + e);
    return __builtin_fmaf(2.0f, r, -1.0f);
}

__global__ __launch_bounds__(64, 1)
void lstm_pair_scan(const float* __restrict__ x,
                    const float* __restrict__ W_ih,
                    const float* __restrict__ W_hh,
                    const float* __restrict__ b_ih,
                    const float* __restrict__ b_hh,
                    const float* __restrict__ W_lin,
                    const float* __restrict__ b_lin,
                    float* __restrict__ out,
                    int T) {
    // h_hist[row][half*32 + col]; col is XOR-swizzled by (row & 28) to keep
    // the per-chunk epilogue (row varies across lanes) nearly conflict-free
    // while preserving 16B contiguity for ds_read_b128.
    __shared__ float h_hist[CHUNK][64];
    __shared__ float x_sh[64];

    const int lane = threadIdx.x;   // 0..63
    const int j    = lane & 31;     // hidden unit
    const int half = lane >> 5;     // which batch of the pair
    const int b    = (blockIdx.x << 1) + half;

    // ---- load per-lane weights: W_hh rows j (i), 32+j (f), 64+j (g), 96+j (o)
    f2 wi[16], wf[16], wg[16], wo[16];
    {
        const f4* Ri = (const f4*)(W_hh + (0  + j) * HID);
        const f4* Rf = (const f4*)(W_hh + (32 + j) * HID);
        const f4* Rg = (const f4*)(W_hh + (64 + j) * HID);
        const f4* Ro = (const f4*)(W_hh + (96 + j) * HID);
#pragma unroll
        for (int m = 0; m < 8; ++m) {
            f4 v;
            v = Ri[m]; wi[2*m] = {v.x, v.y}; wi[2*m+1] = {v.z, v.w};
            v = Rf[m]; wf[2*m] = {v.x, v.y}; wf[2*m+1] = {v.z, v.w};
            v = Rg[m]; wg[2*m] = {v.x, v.y}; wg[2*m+1] = {v.z, v.w};
            v = Ro[m]; wo[2*m] = {v.x, v.y}; wo[2*m+1] = {v.z, v.w};
        }
    }
    const float wih_i = W_ih[j],      bi = b_ih[j]      + b_hh[j];
    const float wih_f = W_ih[32 + j], bf = b_ih[32 + j] + b_hh[32 + j];
    const float wih_g = W_ih[64 + j], bg = b_ih[64 + j] + b_hh[64 + j];
    const float wih_o = W_ih[96 + j], bo = b_ih[96 + j] + b_hh[96 + j];
    const float blin  = b_lin[0];

    // h_{-1} = 0 lives in ring slot CHUNK-1 (swizzled column for row CHUNK-1)
    h_hist[CHUNK - 1][(half << 5) + (j ^ ((CHUNK - 1) & 28))] = 0.0f;
    float c = 0.0f;

    const float* xb_ptr = x   + (size_t)b * T;
    float*       ob_ptr = out + (size_t)b * T;

    for (int t0 = 0; t0 < T; t0 += CHUNK) {
        float xv = xb_ptr[t0 + j];      // lane j holds x[b][t0+j]
        x_sh[lane] = xv;

#pragma unroll 4
        for (int tt = 0; tt < CHUNK; ++tt) {
            const int rs = (tt + CHUNK - 1) & (CHUNK - 1);  // row of h_{t-1}
            // broadcast x_t for my batch (same-address LDS read per half)
            float xb = x_sh[(half << 5) + tt];

            f2 ai = {0.f, 0.f}, af2 = {0.f, 0.f}, ag = {0.f, 0.f}, ao = {0.f, 0.f};
            const float* hrow = &h_hist[rs][half << 5];
            const int    sw   = rs & 28;  // row swizzle (keeps 16B groups intact)
#pragma unroll
            for (int m = 0; m < 8; ++m) {
                // physical base (4m ^ sw) yields LOGICAL h[4m..4m+3]
                f4 h4 = *(const f4*)(hrow + ((4 * m) ^ sw));
                f2 h01 = {h4.x, h4.y}, h23 = {h4.z, h4.w};
                ai  = __builtin_elementwise_fma(wi[2*m],   h01, ai);
                af2 = __builtin_elementwise_fma(wf[2*m],   h01, af2);
                ag  = __builtin_elementwise_fma(wg[2*m],   h01, ag);
                ao  = __builtin_elementwise_fma(wo[2*m],   h01, ao);
                ai  = __builtin_elementwise_fma(wi[2*m+1], h23, ai);
                af2 = __builtin_elementwise_fma(wf[2*m+1], h23, af2);
                ag  = __builtin_elementwise_fma(wg[2*m+1], h23, ag);
                ao  = __builtin_elementwise_fma(wo[2*m+1], h23, ao);
            }
            float gi = fsig (ai.x  + ai.y  + __builtin_fmaf(xb, wih_i, bi));
            float gf = fsig (af2.x + af2.y + __builtin_fmaf(xb, wih_f, bf));
            float gg = ftanh(ag.x  + ag.y  + __builtin_fmaf(xb, wih_g, bg));
            float go = fsig (ao.x  + ao.y  + __builtin_fmaf(xb, wih_o, bo));

            c = __builtin_fmaf(gf, c, gi * gg);
            float h = go * ftanh(c);

            // store h_t into ring slot tt (swizzled column)
            h_hist[tt][(half << 5) + (j ^ (tt & 28))] = h;
        }

        // ---- epilogue: out[b][t0+t'] = x + sum_j W_lin[j]*h[t'][j] + b_lin
        // lane -> t' = j, batch = half. Reads row j with its own swizzle; the
        // XOR cancels so each b128 yields logical h[4m..4m+3], so W_lin
        // indices stay uniform (s_load).
        {
            const float* hrow = &h_hist[j][half << 5];
            const int    sw   = j & 28;
            float acc = 0.0f;
#pragma unroll
            for (int m = 0; m < 8; ++m) {
                f4 h4 = *(const f4*)(hrow + ((4 * m) ^ sw));
                acc = __builtin_fmaf(W_lin[4*m + 0], h4.x, acc);
                acc = __builtin_fmaf(W_lin[4*m + 1], h4.y, acc);
                acc = __builtin_fmaf(W_lin[4*m + 2], h4.z, acc);
                acc = __builtin_fmaf(W_lin[4*m + 3], h4.w, acc);
            }
            ob_ptr[t0 + j] = xv + acc + blin;
        }
    }
}

extern "C" void kernel_launch(void* const* d_in, const int* in_sizes, int n_in,
                              void* d_out, int out_size, void* d_ws, size_t ws_size,
                              hipStream_t stream) {
    const float* x     = (const float*)d_in[0];
    const float* W_ih  = (const float*)d_in[1];
    const float* W_hh  = (const float*)d_in[2];
    const float* b_ih  = (const float*)d_in[3];
    const float* b_hh  = (const float*)d_in[4];
    const float* W_lin = (const float*)d_in[5];
    const float* b_lin = (const float*)d_in[6];
    float* out = (float*)d_out;

    const int B = 64;
    const int T = in_sizes[0] / B;   // 16384

    dim3 grid(B / 2);                // one wave per batch pair
    dim3 block(64);
    lstm_pair_scan<<<grid, block, 0, stream>>>(x, W_ih, W_hh, b_ih, b_hh,
                                               W_lin, b_lin, out, T);
}

// Round 2
// 3572.548 us; speedup vs baseline: 1.3024x; 1.3024x over previous
//
#include <hip/hip_runtime.h>

// LSTM scan, B=64, T=16384, H=32, I=O=1, fp32.
// ONE WAVE PER BATCH (64 blocks x 64 threads). Latency-bound serial scan:
// the only metric that matters is the per-step dependence chain.
//
// Lane mapping: j = lane&31 (hidden unit), half = lane>>5.
//   A-lanes (half=0): compute gates i (row j)    and g (row 64+j)
//   B-lanes (half=1): compute gates f (row 32+j) and o (row 96+j)
// Same instruction stream for both halves (per-lane weights/constants), so
// the per-step matvec is 32 pk_fma instead of 64.
//
// h_{t-1} broadcast: 32 v_readlane -> wave-uniform scalars (no LDS latency
// on the chain). Cell state c lives in B-lanes; the single cross-half move
// is p = i*g via __shfl_xor(p, 32).
//
// Output projection: B-lanes ds_write h each step (fire-and-forget); per
// 32-step chunk an epilogue reads the history (row stride 65 -> conflict
// free) and dots with W_lin (wave-uniform SGPRs).

#define HID 32
#define CHUNK 32

typedef float f2 __attribute__((ext_vector_type(2)));
typedef float f4 __attribute__((ext_vector_type(4)));

__device__ __forceinline__ float rl(float v, int lane) {
    return __int_as_float(__builtin_amdgcn_readlane(__float_as_int(v), lane));
}

__device__ __forceinline__ float fsig(float v) {
    // sigmoid(v) = 1 / (1 + exp2(-v*log2(e)))
    float e = __builtin_amdgcn_exp2f(v * -1.44269504088896340736f);
    return __builtin_amdgcn_rcpf(1.0f + e);
}
__device__ __forceinline__ float ftanh(float v) {
    // tanh(v) = 2/(1+exp2(-2v*log2(e))) - 1
    float e = __builtin_amdgcn_exp2f(v * -2.88539008177792681472f);
    float r = __builtin_amdgcn_rcpf(1.0f + e);
    return __builtin_fmaf(2.0f, r, -1.0f);
}

__global__ __launch_bounds__(64, 1)
void lstm_wave_scan(const float* __restrict__ x,
                    const float* __restrict__ W_ih,
                    const float* __restrict__ W_hh,
                    const float* __restrict__ b_ih,
                    const float* __restrict__ b_hh,
                    const float* __restrict__ W_lin,
                    const float* __restrict__ b_lin,
                    float* __restrict__ out,
                    int T) {
    __shared__ float h_hist[CHUNK][65];   // row stride 65: epilogue conflict-free

    const int lane = threadIdx.x;
    const int j    = lane & 31;
    const int half = lane >> 5;
    const int b    = blockIdx.x;

    // Per-lane gate rows.
    const int row1 = j + (half << 5);         // A: i-row j     B: f-row 32+j
    const int row2 = 64 + j + (half << 5);    // A: g-row 64+j  B: o-row 96+j

    f2 w1[16], w2[16];
    {
        const f4* R1 = (const f4*)(W_hh + row1 * HID);
        const f4* R2 = (const f4*)(W_hh + row2 * HID);
#pragma unroll
        for (int m = 0; m < 8; ++m) {
            f4 v;
            v = R1[m]; w1[2*m] = {v.x, v.y}; w1[2*m+1] = {v.z, v.w};
            v = R2[m]; w2[2*m] = {v.x, v.y}; w2[2*m+1] = {v.z, v.w};
        }
    }
    const float wih1 = W_ih[row1], bb1 = b_ih[row1] + b_hh[row1];
    const float wih2 = W_ih[row2], bb2 = b_ih[row2] + b_hh[row2];

    // act2 per-lane parameterization: A-lanes tanh (for g), B-lanes sigmoid (for o).
    //   act2(v) = pb * rcp(1 + exp2(pa * v)) + pc
    const float pa = half ? -1.44269504088896340736f : -2.88539008177792681472f;
    const float pb = half ? 1.0f : 2.0f;
    const float pc = half ? 0.0f : -1.0f;

    const float blin = b_lin[0];

    float c = 0.0f;           // valid in B-lanes only
    f2 hp[16];                // broadcast h_{t-1}, wave-uniform values
#pragma unroll
    for (int k = 0; k < 16; ++k) hp[k] = {0.0f, 0.0f};

    const float* xb = x   + (size_t)b * T;
    float*       ob = out + (size_t)b * T;

    float xv = xb[j];         // chunk 0 x values, lanes duplicated across halves

    for (int t0 = 0; t0 < T; t0 += CHUNK) {
        // Prefetch next chunk's x (wraps to 0 on the last chunk; value unused).
        int t0n = t0 + CHUNK; if (t0n >= T) t0n = 0;
        float xv_next = xb[t0n + j];

#pragma unroll 4
        for (int tt = 0; tt < CHUNK; ++tt) {
            const float sx = rl(xv, tt);  // wave-uniform x_t

            // Gate pre-activations: init with x/bias contribution, then W_hh . h
            f2 acc1 = { __builtin_fmaf(sx, wih1, bb1), 0.0f };
            f2 acc2 = { __builtin_fmaf(sx, wih2, bb2), 0.0f };
#pragma unroll
            for (int m = 0; m < 16; ++m) {
                acc1 = __builtin_elementwise_fma(w1[m], hp[m], acc1);
                acc2 = __builtin_elementwise_fma(w2[m], hp[m], acc2);
            }
            const float g1 = acc1.x + acc1.y;   // A: i-pre   B: f-pre
            const float g2 = acc2.x + acc2.y;   // A: g-pre   B: o-pre

            const float a1 = fsig(g1);          // A: i       B: f
            const float e2 = __builtin_amdgcn_exp2f(g2 * pa);
            const float a2 = __builtin_fmaf(pb, __builtin_amdgcn_rcpf(1.0f + e2), pc);
                                                // A: g=tanh  B: o=sigmoid

            const float p = a1 * a2;            // A: i*g     B: (unused)
            const float q = __shfl_xor(p, 32, 64);

            c = __builtin_fmaf(a1, c, q);       // B: f*c + i*g   (A: garbage, bounded)
            const float h = a2 * ftanh(c);      // B: o*tanh(c)   (A: garbage)

            h_hist[tt][lane] = h;               // B-half columns 32..63 are the real h

            // Broadcast h_t for the next step (reads B-lanes, exec-independent).
#pragma unroll
            for (int k = 0; k < 16; ++k)
                hp[k] = { rl(h, 32 + 2*k), rl(h, 32 + 2*k + 1) };
        }

        // ---- epilogue: out[b][t0+t'] = x + W_lin . h_t' + b_lin, t' = j
        {
            float facc = 0.0f;
#pragma unroll
            for (int k = 0; k < 32; ++k)
                facc = __builtin_fmaf(W_lin[k], h_hist[j][32 + k], facc);
            if (half == 0)
                ob[t0 + j] = xv + facc + blin;
        }

        xv = xv_next;
    }
}

extern "C" void kernel_launch(void* const* d_in, const int* in_sizes, int n_in,
                              void* d_out, int out_size, void* d_ws, size_t ws_size,
                              hipStream_t stream) {
    const float* x     = (const float*)d_in[0];
    const float* W_ih  = (const float*)d_in[1];
    const float* W_hh  = (const float*)d_in[2];
    const float* b_ih  = (const float*)d_in[3];
    const float* b_hh  = (const float*)d_in[4];
    const float* W_lin = (const float*)d_in[5];
    const float* b_lin = (const float*)d_in[6];
    float* out = (float*)d_out;

    const int B = 64;
    const int T = in_sizes[0] / B;   // 16384

    dim3 grid(B);                    // one wave per batch
    dim3 block(64);
    lstm_wave_scan<<<grid, block, 0, stream>>>(x, W_ih, W_hh, b_ih, b_hh,
                                               W_lin, b_lin, out, T);
}

// Round 4
// 3276.139 us; speedup vs baseline: 1.4202x; 1.0905x over previous
//
#include <hip/hip_runtime.h>

// LSTM scan, B=64, T=16384, H=32, I=O=1, fp32.
// ONE WAVE PER BATCH (64 blocks x 64 threads). Pure latency problem: wall
// time = T x per-step dependence-chain length.
//
// Round-4: cross-half exchange via the __builtin_amdgcn_permlane32_swap
// builtin (compiler inserts the gfx950 VALU->permlane hazard wait states
// that raw inline asm silently skipped in round 3 -> absmax 0.359 fail).
// Recombination is the exact XOR identity: the swap's two results hold
// {p_A everywhere, p_B everywhere} in some order, so r0^r1^p_own is
// bit-exactly the OTHER half's p under either orientation.
//
// Lane mapping: j = lane&31, half = lane>>5.
//   A-lanes (half=0): gates i (row j)    and g (row 64+j)
//   B-lanes (half=1): gates f (row 32+j) and o (row 96+j)
// c and h are valid in B-lanes (A-lanes compute bounded garbage: their
// "c" update is c = i*c + f*o with i in (0,1) -> contraction, no overflow).

#define HID 32
#define CHUNK 32

typedef float f2 __attribute__((ext_vector_type(2)));
typedef float f4 __attribute__((ext_vector_type(4)));
typedef unsigned int u32x2 __attribute__((ext_vector_type(2)));

#if defined(__has_builtin)
#if __has_builtin(__builtin_amdgcn_permlane32_swap)
#define HAVE_PLSWAP 1
#endif
#endif

__device__ __forceinline__ float rl(float v, int lane) {
    return __int_as_float(__builtin_amdgcn_readlane(__float_as_int(v), lane));
}

__device__ __forceinline__ float fsig(float v) {
    float e = __builtin_amdgcn_exp2f(v * -1.44269504088896340736f);
    return __builtin_amdgcn_rcpf(1.0f + e);
}
__device__ __forceinline__ float ftanh(float v) {
    float e = __builtin_amdgcn_exp2f(v * -2.88539008177792681472f);
    float r = __builtin_amdgcn_rcpf(1.0f + e);
    return __builtin_fmaf(2.0f, r, -1.0f);
}

// Exchange p across wave halves: every lane gets the other half's p
// (for its own j). VALU-only on gfx950; DS-pipe fallback otherwise.
__device__ __forceinline__ float cross_half(float p) {
#ifdef HAVE_PLSWAP
    const unsigned pu = __float_as_uint(p);
    u32x2 r = __builtin_amdgcn_permlane32_swap(pu, pu, false, false);
    return __uint_as_float(r[0] ^ r[1] ^ pu);   // exact, orientation-independent
#else
    return __shfl_xor(p, 32, 64);
#endif
}

__global__ __launch_bounds__(64, 1)
void lstm_wave_scan(const float* __restrict__ x,
                    const float* __restrict__ W_ih,
                    const float* __restrict__ W_hh,
                    const float* __restrict__ b_ih,
                    const float* __restrict__ b_hh,
                    const float* __restrict__ W_lin,
                    const float* __restrict__ b_lin,
                    float* __restrict__ out,
                    int T) {
    __shared__ float h_hist[CHUNK][65];   // row stride 65: epilogue conflict-free

    const int lane = threadIdx.x;
    const int j    = lane & 31;
    const int half = lane >> 5;
    const int b    = blockIdx.x;

    const int row1 = j + (half << 5);         // A: i-row j     B: f-row 32+j
    const int row2 = 64 + j + (half << 5);    // A: g-row 64+j  B: o-row 96+j

    f2 w1[16], w2[16];
    {
        const f4* R1 = (const f4*)(W_hh + row1 * HID);
        const f4* R2 = (const f4*)(W_hh + row2 * HID);
#pragma unroll
        for (int m = 0; m < 8; ++m) {
            f4 v;
            v = R1[m]; w1[2*m] = {v.x, v.y}; w1[2*m+1] = {v.z, v.w};
            v = R2[m]; w2[2*m] = {v.x, v.y}; w2[2*m+1] = {v.z, v.w};
        }
    }
    const float wih1 = W_ih[row1], bb1 = b_ih[row1] + b_hh[row1];
    const float wih2 = W_ih[row2], bb2 = b_ih[row2] + b_hh[row2];

    // act2: A-lanes tanh (g), B-lanes sigmoid (o):
    //   act2(v) = pb * rcp(1 + exp2(pa*v)) + pc
    const float pa = half ? -1.44269504088896340736f : -2.88539008177792681472f;
    const float pb = half ? 1.0f : 2.0f;
    const float pc = half ? 0.0f : -1.0f;

    const float blin = b_lin[0];

    float c = 0.0f;     // B-lanes: cell state (A-lanes: bounded garbage)
    float h = 0.0f;     // B-lanes: hidden state h_{t-1}

    const float* xb = x   + (size_t)b * T;
    float*       ob = out + (size_t)b * T;

    float xv = xb[j];

    for (int t0 = 0; t0 < T; t0 += CHUNK) {
        int t0n = t0 + CHUNK; if (t0n >= T) t0n = 0;
        float xv_next = xb[t0n + j];

#pragma unroll 8
        for (int tt = 0; tt < CHUNK; ++tt) {
            const float sx = rl(xv, tt);  // wave-uniform x_t

            f2 acc1 = { __builtin_fmaf(sx, wih1, bb1), 0.0f };
            f2 acc2 = { __builtin_fmaf(sx, wih2, bb2), 0.0f };
            // Matvec with fused h-broadcast: readlane pairs feed their FMAs
            // directly so the chain restarts right after h, not after all 32
            // readlanes.
#pragma unroll
            for (int m = 0; m < 16; ++m) {
                f2 hm = { rl(h, 32 + 2*m), rl(h, 32 + 2*m + 1) };
                acc1 = __builtin_elementwise_fma(w1[m], hm, acc1);
                acc2 = __builtin_elementwise_fma(w2[m], hm, acc2);
            }
            const float g1 = acc1.x + acc1.y;   // A: i-pre   B: f-pre
            const float g2 = acc2.x + acc2.y;   // A: g-pre   B: o-pre

            const float a1 = fsig(g1);          // A: i       B: f
            const float e2 = __builtin_amdgcn_exp2f(g2 * pa);
            const float a2 = __builtin_fmaf(pb, __builtin_amdgcn_rcpf(1.0f + e2), pc);
                                                // A: g       B: o

            const float p = a1 * a2;            // A: i*g     B: f*o
            const float q = cross_half(p);      // A: f*o     B: i*g

            c = __builtin_fmaf(a1, c, q);       // B: f*c + i*g
            h = a2 * ftanh(c);                  // B: o*tanh(c)

            h_hist[tt][lane] = h;               // cols 32..63 hold the real h
        }

        // ---- epilogue: out[b][t0+t'] = x + W_lin . h_t' + b_lin, t' = j
        {
            float facc = 0.0f;
#pragma unroll
            for (int k = 0; k < 32; ++k)
                facc = __builtin_fmaf(W_lin[k], h_hist[j][32 + k], facc);
            if (half == 0)
                ob[t0 + j] = xv + facc + blin;
        }

        xv = xv_next;
    }
}

extern "C" void kernel_launch(void* const* d_in, const int* in_sizes, int n_in,
                              void* d_out, int out_size, void* d_ws, size_t ws_size,
                              hipStream_t stream) {
    const float* x     = (const float*)d_in[0];
    const float* W_ih  = (const float*)d_in[1];
    const float* W_hh  = (const float*)d_in[2];
    const float* b_ih  = (const float*)d_in[3];
    const float* b_hh  = (const float*)d_in[4];
    const float* W_lin = (const float*)d_in[5];
    const float* b_lin = (const float*)d_in[6];
    float* out = (float*)d_out;

    const int B = 64;
    const int T = in_sizes[0] / B;   // 16384

    dim3 grid(B);
    dim3 block(64);
    lstm_wave_scan<<<grid, block, 0, stream>>>(x, W_ih, W_hh, b_ih, b_hh,
                                               W_lin, b_lin, out, T);
}